// Round 1
// baseline (350.900 us; speedup 1.0000x reference)
//
#include <hip/hip_runtime.h>
#include <math.h>

// Fused: 8-level dense grid trilinear encode (input_dim=3, level_dim=2)
// + MLP 16->16 (ReLU) -> 16->16 (ReLU) -> 16->1, all fp32.
//
// SIDES/OFFSETS are exact integers (sum of cubes = 85268 = TOTAL_PARAMS).
// SCALES are computed on host in double precision to match the Python
// reference's float64 -> float32 cast.

struct EncParams {
    float scale[8];
};

__global__ __launch_bounds__(256) void sdf_fused_kernel(
    const float* __restrict__ x,
    const float* __restrict__ table,
    const float* __restrict__ W0,
    const float* __restrict__ W1,
    const float* __restrict__ W2,
    float* __restrict__ out,
    int N, EncParams ep)
{
    // side per level, and cumulative row offsets into the table
    constexpr int SIDE[8] = {9, 11, 13, 16, 19, 23, 28, 33};
    constexpr int OFF[8]  = {0, 729, 2060, 4257, 8353, 15212, 27379, 49331};

    __shared__ __align__(16) float sW0[256];
    __shared__ __align__(16) float sW1[256];
    __shared__ __align__(16) float sW2[16];

    const int t = threadIdx.x;
    sW0[t] = W0[t];
    sW1[t] = W1[t];
    if (t < 16) sW2[t] = W2[t];
    __syncthreads();

    const int gid = blockIdx.x * 256 + t;
    if (gid >= N) return;

    const float px = x[3 * gid + 0];
    const float py = x[3 * gid + 1];
    const float pz = x[3 * gid + 2];

    float h[16];

    const float2* __restrict__ tb2 = reinterpret_cast<const float2*>(table);

    #pragma unroll
    for (int l = 0; l < 8; ++l) {
        const int side  = SIDE[l];
        const int side2 = side * side;
        const float s = ep.scale[l];
        const float fx = px * s + 0.5f;
        const float fy = py * s + 0.5f;
        const float fz = pz * s + 0.5f;
        const float gx = floorf(fx), gy = floorf(fy), gz = floorf(fz);
        const float rx = fx - gx, ry = fy - gy, rz = fz - gz;
        const int ix = (int)gx, iy = (int)gy, iz = (int)gz;
        const int base = OFF[l] + ix + iy * side + iz * side2;

        const float wx0 = 1.0f - rx;
        const float wy0 = 1.0f - ry;
        const float wz0 = 1.0f - rz;

        float a0 = 0.0f, a1 = 0.0f;
        #pragma unroll
        for (int dz = 0; dz < 2; ++dz) {
            const float wz = dz ? rz : wz0;
            #pragma unroll
            for (int dy = 0; dy < 2; ++dy) {
                const float wyz = (dy ? ry : wy0) * wz;
                const int r = base + dy * side + dz * side2;
                // two adjacent x-corners = two consecutive table rows
                const float2 f0 = tb2[r];
                const float2 f1 = tb2[r + 1];
                const float w0 = wyz * wx0;
                const float w1 = wyz * rx;
                a0 += w0 * f0.x + w1 * f1.x;
                a1 += w0 * f0.y + w1 * f1.y;
            }
        }
        h[2 * l + 0] = a0;
        h[2 * l + 1] = a1;
    }

    // ---- MLP (fp32, weights broadcast from LDS) ----
    float h1[16];
    #pragma unroll
    for (int j = 0; j < 16; ++j) {
        float a = 0.0f;
        #pragma unroll
        for (int i4 = 0; i4 < 4; ++i4) {
            const float4 w = *reinterpret_cast<const float4*>(&sW0[j * 16 + 4 * i4]);
            a += h[4 * i4 + 0] * w.x + h[4 * i4 + 1] * w.y
               + h[4 * i4 + 2] * w.z + h[4 * i4 + 3] * w.w;
        }
        h1[j] = fmaxf(a, 0.0f);
    }

    float h2[16];
    #pragma unroll
    for (int j = 0; j < 16; ++j) {
        float a = 0.0f;
        #pragma unroll
        for (int i4 = 0; i4 < 4; ++i4) {
            const float4 w = *reinterpret_cast<const float4*>(&sW1[j * 16 + 4 * i4]);
            a += h1[4 * i4 + 0] * w.x + h1[4 * i4 + 1] * w.y
               + h1[4 * i4 + 2] * w.z + h1[4 * i4 + 3] * w.w;
        }
        h2[j] = fmaxf(a, 0.0f);
    }

    float o = 0.0f;
    #pragma unroll
    for (int i = 0; i < 16; ++i) o += h2[i] * sW2[i];

    out[gid] = o;
}

extern "C" void kernel_launch(void* const* d_in, const int* in_sizes, int n_in,
                              void* d_out, int out_size, void* d_ws, size_t ws_size,
                              hipStream_t stream) {
    const float* x     = (const float*)d_in[0];
    const float* table = (const float*)d_in[1];
    const float* W0    = (const float*)d_in[2];
    const float* W1    = (const float*)d_in[3];
    const float* W2    = (const float*)d_in[4];
    float* out = (float*)d_out;

    const int N = in_sizes[0] / 3;

    EncParams ep;
    const double g = pow(4.0, 1.0 / 7.0);
    for (int l = 0; l < 8; ++l) {
        ep.scale[l] = (float)(8.0 * pow(g, (double)l) - 1.0);
    }

    const int blocks = (N + 255) / 256;
    hipLaunchKernelGGL(sdf_fused_kernel, dim3(blocks), dim3(256), 0, stream,
                       x, table, W0, W1, W2, out, N, ep);
}

// Round 2
// 295.005 us; speedup vs baseline: 1.1895x; 1.1895x over previous
//
#include <hip/hip_runtime.h>
#include <math.h>

// Fused: 8-level dense grid trilinear encode (input_dim=3, level_dim=2)
// + MLP 16->16 (ReLU) -> 16->16 (ReLU) -> 16->1, fp32 with packed v_pk_fma_f32.
//
// Round-2 changes vs round 1 (which was gather-transaction-bound, 396us,
// VALUBusy 36%, HBM 1.4%):
//  - corner-pair rows (r, r+1) loaded as ONE 16B dwordx4 (8B-aligned; CDNA
//    handles unaligned global vector loads in HW) -> halves L1 transactions
//  - levels 0..2 (4257 rows, 34KB) staged in LDS -> their gathers leave L1
//  - packed fp32 (ext_vector_type(2)) for interp + MLP -> ~2x fewer FMA instrs
//  - block=512: LDS 37KB -> 4 blocks/CU, up to 32 waves/CU

typedef float v2f __attribute__((ext_vector_type(2)));

struct EncParams {
    float scale[8];
};

__global__ __launch_bounds__(512) void sdf_fused_kernel(
    const float* __restrict__ x,
    const float* __restrict__ table,
    const float* __restrict__ W0,
    const float* __restrict__ W1,
    const float* __restrict__ W2,
    float* __restrict__ out,
    int N, EncParams ep)
{
    constexpr int SIDE[8] = {9, 11, 13, 16, 19, 23, 28, 33};
    constexpr int OFF[8]  = {0, 729, 2060, 4257, 8353, 15212, 27379, 49331};
    constexpr int NROWS_LDS = 4257;   // levels 0..2 staged in LDS (34,056 B)

    __shared__ __align__(16) float sTab[2 * NROWS_LDS];
    __shared__ __align__(16) float sW0t[256];   // transposed: [i][j]
    __shared__ __align__(16) float sW1t[256];   // transposed: [i][j]
    __shared__ __align__(16) float sW2[16];

    const int t = threadIdx.x;

    if (t < 256) {
        // t = j*16 + i in row-major W[j][i]; store transposed [i][j]
        sW0t[(t & 15) * 16 + (t >> 4)] = W0[t];
        sW1t[(t & 15) * 16 + (t >> 4)] = W1[t];
        if (t < 16) sW2[t] = W2[t];
    }
    {
        const float2* tb2 = reinterpret_cast<const float2*>(table);
        float2* sT2 = reinterpret_cast<float2*>(sTab);
        for (int i = t; i < NROWS_LDS; i += 512) sT2[i] = tb2[i];
    }
    __syncthreads();

    const int gid = blockIdx.x * 512 + t;
    if (gid >= N) return;

    const float px = x[3 * gid + 0];
    const float py = x[3 * gid + 1];
    const float pz = x[3 * gid + 2];

    v2f hl[8];   // per-level 2-dim features

    const float2* sT2 = reinterpret_cast<const float2*>(sTab);

    #pragma unroll
    for (int l = 0; l < 8; ++l) {
        const int side  = SIDE[l];
        const int side2 = side * side;
        const float s = ep.scale[l];
        const float fx = px * s + 0.5f;
        const float fy = py * s + 0.5f;
        const float fz = pz * s + 0.5f;
        const float gx = floorf(fx), gy = floorf(fy), gz = floorf(fz);
        const float rx = fx - gx, ry = fy - gy, rz = fz - gz;
        const int ix = (int)gx, iy = (int)gy, iz = (int)gz;
        const int base = OFF[l] + ix + iy * side + iz * side2;

        const float wx0 = 1.0f - rx;
        const float wy0 = 1.0f - ry;
        const float wz0 = 1.0f - rz;

        v2f acc = {0.0f, 0.0f};

        if (l < 3) {
            // LDS path (levels 0..2)
            #pragma unroll
            for (int dz = 0; dz < 2; ++dz) {
                const float wz = dz ? rz : wz0;
                #pragma unroll
                for (int dy = 0; dy < 2; ++dy) {
                    const float wyz = (dy ? ry : wy0) * wz;
                    const int r = base + dy * side + dz * side2;
                    const float2 f0 = sT2[r];
                    const float2 f1 = sT2[r + 1];
                    const v2f v0 = {f0.x, f0.y};
                    const v2f v1 = {f1.x, f1.y};
                    acc += (wyz * wx0) * v0 + (wyz * rx) * v1;
                }
            }
        } else {
            // global path (levels 3..7): one 16B load per corner-pair.
            // addr = table + 2*r floats -> always 8B aligned; HW handles
            // dwordx4 at 8B alignment.
            #pragma unroll
            for (int dz = 0; dz < 2; ++dz) {
                const float wz = dz ? rz : wz0;
                #pragma unroll
                for (int dy = 0; dy < 2; ++dy) {
                    const float wyz = (dy ? ry : wy0) * wz;
                    const int r = base + dy * side + dz * side2;
                    const float4 f = *reinterpret_cast<const float4*>(table + 2 * r);
                    const v2f v0 = {f.x, f.y};
                    const v2f v1 = {f.z, f.w};
                    acc += (wyz * wx0) * v0 + (wyz * rx) * v1;
                }
            }
        }
        hl[l] = acc;
    }

    // ---- MLP, packed fp32: 2 output neurons per accumulator ----
    v2f a[8];

    // layer 0: a[j2] = sum_i h_i * W0t[i][2j2:2j2+2]
    #pragma unroll
    for (int j = 0; j < 8; ++j) a[j] = (v2f){0.0f, 0.0f};
    #pragma unroll
    for (int i2 = 0; i2 < 8; ++i2) {
        const float h0 = hl[i2].x;
        const float h1 = hl[i2].y;
        const float4* w0 = reinterpret_cast<const float4*>(&sW0t[(2 * i2) * 16]);
        const float4* w1 = reinterpret_cast<const float4*>(&sW0t[(2 * i2 + 1) * 16]);
        #pragma unroll
        for (int q = 0; q < 4; ++q) {
            const float4 wa = w0[q];
            const float4 wb = w1[q];
            a[2 * q]     += h0 * (v2f){wa.x, wa.y};
            a[2 * q + 1] += h0 * (v2f){wa.z, wa.w};
            a[2 * q]     += h1 * (v2f){wb.x, wb.y};
            a[2 * q + 1] += h1 * (v2f){wb.z, wb.w};
        }
    }
    const v2f zz = {0.0f, 0.0f};
    v2f h1v[8];
    #pragma unroll
    for (int j = 0; j < 8; ++j) h1v[j] = __builtin_elementwise_max(a[j], zz);

    // layer 1
    #pragma unroll
    for (int j = 0; j < 8; ++j) a[j] = (v2f){0.0f, 0.0f};
    #pragma unroll
    for (int i2 = 0; i2 < 8; ++i2) {
        const float h0 = h1v[i2].x;
        const float h1 = h1v[i2].y;
        const float4* w0 = reinterpret_cast<const float4*>(&sW1t[(2 * i2) * 16]);
        const float4* w1 = reinterpret_cast<const float4*>(&sW1t[(2 * i2 + 1) * 16]);
        #pragma unroll
        for (int q = 0; q < 4; ++q) {
            const float4 wa = w0[q];
            const float4 wb = w1[q];
            a[2 * q]     += h0 * (v2f){wa.x, wa.y};
            a[2 * q + 1] += h0 * (v2f){wa.z, wa.w};
            a[2 * q]     += h1 * (v2f){wb.x, wb.y};
            a[2 * q + 1] += h1 * (v2f){wb.z, wb.w};
        }
    }

    // layer 2: out = sum_i relu(a_i) * W2[i]
    v2f acco = {0.0f, 0.0f};
    #pragma unroll
    for (int j = 0; j < 8; ++j) {
        const v2f h2 = __builtin_elementwise_max(a[j], zz);
        const v2f w2 = {sW2[2 * j], sW2[2 * j + 1]};
        acco += h2 * w2;
    }
    out[gid] = acco.x + acco.y;
}

extern "C" void kernel_launch(void* const* d_in, const int* in_sizes, int n_in,
                              void* d_out, int out_size, void* d_ws, size_t ws_size,
                              hipStream_t stream) {
    const float* x     = (const float*)d_in[0];
    const float* table = (const float*)d_in[1];
    const float* W0    = (const float*)d_in[2];
    const float* W1    = (const float*)d_in[3];
    const float* W2    = (const float*)d_in[4];
    float* out = (float*)d_out;

    const int N = in_sizes[0] / 3;

    EncParams ep;
    const double g = pow(4.0, 1.0 / 7.0);
    for (int l = 0; l < 8; ++l) {
        ep.scale[l] = (float)(8.0 * pow(g, (double)l) - 1.0);
    }

    const int blocks = (N + 511) / 512;
    hipLaunchKernelGGL(sdf_fused_kernel, dim3(blocks), dim3(512), 0, stream,
                       x, table, W0, W1, W2, out, N, ep);
}